// Round 1
// baseline (1641.500 us; speedup 1.0000x reference)
//
#include <hip/hip_runtime.h>

static constexpr int kT = 8192;
static constexpr int kH = 2048;
static constexpr int kI = 1408;
static constexpr int kE = 16;

typedef __bf16 bf16x8 __attribute__((ext_vector_type(8)));
typedef float floatx4 __attribute__((ext_vector_type(4)));

__device__ __forceinline__ __bf16 f2bf(float f) { return (__bf16)f; }

// ---------------- x fp32 -> bf16 (8 elems/thread) ----------------
__global__ void cvt_x_kernel(const float* __restrict__ x, __bf16* __restrict__ xb) {
    size_t i = ((size_t)blockIdx.x * 256 + threadIdx.x) * 8;
    float4 v0 = *(const float4*)(x + i);
    float4 v1 = *(const float4*)(x + i + 4);
    union { __bf16 b[8]; uint4 u; } o;
    o.b[0] = f2bf(v0.x); o.b[1] = f2bf(v0.y); o.b[2] = f2bf(v0.z); o.b[3] = f2bf(v0.w);
    o.b[4] = f2bf(v1.x); o.b[5] = f2bf(v1.y); o.b[6] = f2bf(v1.z); o.b[7] = f2bf(v1.w);
    *(uint4*)(xb + i) = o.u;
}

// ---------------- gating: fp32 logits, top-2, softmax ----------------
// one wave per token; fp32 so expert selection matches the numpy reference
__global__ __launch_bounds__(256)
void gate_kernel(const float* __restrict__ x, const float* __restrict__ gw,
                 int* __restrict__ t_ids, float* __restrict__ t_w,
                 int* __restrict__ counts) {
    const int lane = threadIdx.x & 63;
    const int t = blockIdx.x * 4 + (threadIdx.x >> 6);
    float acc[kE];
#pragma unroll
    for (int e = 0; e < kE; ++e) acc[e] = 0.f;
    const float* xr = x + (size_t)t * kH;
    for (int h = lane; h < kH; h += 64) {
        const float xv = xr[h];
#pragma unroll
        for (int e = 0; e < kE; ++e) acc[e] += xv * gw[e * kH + h];
    }
#pragma unroll
    for (int e = 0; e < kE; ++e) {
        float v = acc[e];
        for (int off = 32; off > 0; off >>= 1) v += __shfl_xor(v, off, 64);
        acc[e] = v;
    }
    if (lane == 0) {
        int i0 = 0; float l0 = acc[0];
#pragma unroll
        for (int e = 1; e < kE; ++e) if (acc[e] > l0) { l0 = acc[e]; i0 = e; }
        int i1 = -1; float l1 = -3.4e38f;
#pragma unroll
        for (int e = 0; e < kE; ++e) if (e != i0 && acc[e] > l1) { l1 = acc[e]; i1 = e; }
        const float ex = __expf(l1 - l0);          // l1 <= l0, no overflow
        const float inv = 1.f / (1.f + ex);
        t_ids[2 * t] = i0; t_ids[2 * t + 1] = i1;
        t_w[2 * t] = inv;  t_w[2 * t + 1] = ex * inv;
        atomicAdd(counts + i0, 1);
        atomicAdd(counts + i1, 1);
    }
}

// ---------------- tiny exclusive scan over 16 counts ----------------
__global__ void scan_kernel(const int* __restrict__ counts, int* __restrict__ offs,
                            int* __restrict__ fill) {
    if (threadIdx.x == 0) {
        int s = 0;
        for (int e = 0; e < kE; ++e) { offs[e] = s; fill[e] = s; s += counts[e]; }
        offs[kE] = s;
    }
}

// ---------------- scatter token ids into expert buckets ----------------
__global__ void scatter_kernel(const int* __restrict__ t_ids, const float* __restrict__ t_w,
                               int* __restrict__ fill, int* __restrict__ btok,
                               float* __restrict__ bw) {
    int t = blockIdx.x * 256 + threadIdx.x;
    if (t < kT) {
#pragma unroll
        for (int k = 0; k < 2; ++k) {
            int e = t_ids[2 * t + k];
            int pos = atomicAdd(fill + e, 1);
            btok[pos] = t;
            bw[pos] = t_w[2 * t + k];
        }
    }
}

// ---------------- grouped GEMM1: h = silu(Xe@W1^T)*(Xe@Up^T)*w ----------------
// BM=128, BN=64, BK=64; block=256 (4 waves, 2x2), wave tile 64x32.
__global__ __launch_bounds__(256, 2)
void gemm1_kernel(const __bf16* __restrict__ xb, const float* __restrict__ W1,
                  const float* __restrict__ Up, const int* __restrict__ btok,
                  const float* __restrict__ bw, const int* __restrict__ offs,
                  __bf16* __restrict__ hbuf) {
    const int e = blockIdx.z;
    const int seg0 = offs[e];
    const int ne = offs[e + 1] - seg0;
    const int m0 = blockIdx.y * 128;
    if (m0 >= ne) return;
    const int n0 = blockIdx.x * 64;

    __shared__ __align__(16) __bf16 sA[128 * 64];
    __shared__ __align__(16) __bf16 sB1[64 * 64];
    __shared__ __align__(16) __bf16 sB2[64 * 64];

    const int tid = threadIdx.x;

    // A staging: 128 rows x 64 bf16; row = (tid>>3)+32i, col = (tid&7)*8
    const int ar = tid >> 3;
    const int ac = (tid & 7) * 8;
    const __bf16* aptr[4];
#pragma unroll
    for (int i = 0; i < 4; ++i) {
        int rr = m0 + ar + 32 * i;
        if (rr >= ne) rr = ne - 1;                 // clamp: rows discarded in epilogue
        aptr[i] = xb + (size_t)btok[seg0 + rr] * kH + ac;
    }

    // B staging: 64 rows x 64 fp32 -> bf16; row = (tid>>4)+16i, col = (tid&15)*4
    const int brr = tid >> 4;
    const int bcc = (tid & 15) * 4;
    const float* b1p = W1 + ((size_t)e * kI + n0 + brr) * kH + bcc;
    const float* b2p = Up + ((size_t)e * kI + n0 + brr) * kH + bcc;

    const int wid = tid >> 6, lane = tid & 63;
    const int wm = (wid >> 1) * 64, wn = (wid & 1) * 32;
    const int lr = lane & 15;
    const int lk = (lane >> 4) * 8;

    floatx4 acc1[4][2], acc2[4][2];
#pragma unroll
    for (int i = 0; i < 4; ++i)
#pragma unroll
        for (int j = 0; j < 2; ++j) { acc1[i][j] = (floatx4)0.f; acc2[i][j] = (floatx4)0.f; }

    for (int k0 = 0; k0 < kH; k0 += 64) {
        __syncthreads();
#pragma unroll
        for (int i = 0; i < 4; ++i) {
            uint4 v = *(const uint4*)(aptr[i] + k0);
            *(uint4*)(sA + (ar + 32 * i) * 64 + ac) = v;
        }
#pragma unroll
        for (int i = 0; i < 4; ++i) {
            float4 v1 = *(const float4*)(b1p + (size_t)(16 * i) * kH + k0);
            float4 v2 = *(const float4*)(b2p + (size_t)(16 * i) * kH + k0);
            union { __bf16 b[4]; uint2 u; } o1, o2;
            o1.b[0] = f2bf(v1.x); o1.b[1] = f2bf(v1.y); o1.b[2] = f2bf(v1.z); o1.b[3] = f2bf(v1.w);
            o2.b[0] = f2bf(v2.x); o2.b[1] = f2bf(v2.y); o2.b[2] = f2bf(v2.z); o2.b[3] = f2bf(v2.w);
            *(uint2*)(sB1 + (brr + 16 * i) * 64 + bcc) = o1.u;
            *(uint2*)(sB2 + (brr + 16 * i) * 64 + bcc) = o2.u;
        }
        __syncthreads();
#pragma unroll
        for (int ks = 0; ks < 2; ++ks) {
            const int kk = ks * 32 + lk;
            bf16x8 af[4], bf1[2], bf2[2];
#pragma unroll
            for (int i = 0; i < 4; ++i)
                af[i] = *(const bf16x8*)(sA + (wm + i * 16 + lr) * 64 + kk);
#pragma unroll
            for (int j = 0; j < 2; ++j) {
                bf1[j] = *(const bf16x8*)(sB1 + (wn + j * 16 + lr) * 64 + kk);
                bf2[j] = *(const bf16x8*)(sB2 + (wn + j * 16 + lr) * 64 + kk);
            }
#pragma unroll
            for (int i = 0; i < 4; ++i)
#pragma unroll
                for (int j = 0; j < 2; ++j) {
                    acc1[i][j] = __builtin_amdgcn_mfma_f32_16x16x32_bf16(af[i], bf1[j], acc1[i][j], 0, 0, 0);
                    acc2[i][j] = __builtin_amdgcn_mfma_f32_16x16x32_bf16(af[i], bf2[j], acc2[i][j], 0, 0, 0);
                }
        }
    }

    // epilogue: silu(a1)*a2 * route_w -> bf16 h
    const int q4 = (lane >> 4) * 4;
#pragma unroll
    for (int i = 0; i < 4; ++i) {
#pragma unroll
        for (int r = 0; r < 4; ++r) {
            const int row = wm + i * 16 + q4 + r;
            if (m0 + row < ne) {
                const float wrt = bw[seg0 + m0 + row];
                __bf16* hp = hbuf + (size_t)(seg0 + m0 + row) * kI + n0 + wn + (lane & 15);
#pragma unroll
                for (int j = 0; j < 2; ++j) {
                    float a = acc1[i][j][r];
                    float b = acc2[i][j][r];
                    float s = a / (1.f + __expf(-a));
                    hp[j * 16] = f2bf(s * b * wrt);
                }
            }
        }
    }
}

// ---------------- grouped GEMM2: out[tok] += h@W2^T ----------------
__global__ __launch_bounds__(256, 2)
void gemm2_kernel(const __bf16* __restrict__ hbuf, const float* __restrict__ W2,
                  const int* __restrict__ btok, const int* __restrict__ offs,
                  float* __restrict__ out) {
    const int e = blockIdx.z;
    const int seg0 = offs[e];
    const int ne = offs[e + 1] - seg0;
    const int m0 = blockIdx.y * 128;
    if (m0 >= ne) return;
    const int n0 = blockIdx.x * 64;

    __shared__ __align__(16) __bf16 sA[128 * 64];
    __shared__ __align__(16) __bf16 sB[64 * 64];

    const int tid = threadIdx.x;
    const int ar = tid >> 3;
    const int ac = (tid & 7) * 8;
    const __bf16* aptr[4];
#pragma unroll
    for (int i = 0; i < 4; ++i) {
        int rr = m0 + ar + 32 * i;
        if (rr >= ne) rr = ne - 1;
        aptr[i] = hbuf + (size_t)(seg0 + rr) * kI + ac;
    }

    const int brr = tid >> 4;
    const int bcc = (tid & 15) * 4;
    const float* bp = W2 + ((size_t)e * kH + n0 + brr) * kI + bcc;

    const int wid = tid >> 6, lane = tid & 63;
    const int wm = (wid >> 1) * 64, wn = (wid & 1) * 32;
    const int lr = lane & 15;
    const int lk = (lane >> 4) * 8;

    floatx4 acc[4][2];
#pragma unroll
    for (int i = 0; i < 4; ++i)
#pragma unroll
        for (int j = 0; j < 2; ++j) acc[i][j] = (floatx4)0.f;

    for (int k0 = 0; k0 < kI; k0 += 64) {
        __syncthreads();
#pragma unroll
        for (int i = 0; i < 4; ++i) {
            uint4 v = *(const uint4*)(aptr[i] + k0);
            *(uint4*)(sA + (ar + 32 * i) * 64 + ac) = v;
        }
#pragma unroll
        for (int i = 0; i < 4; ++i) {
            float4 v1 = *(const float4*)(bp + (size_t)(16 * i) * kI + k0);
            union { __bf16 b[4]; uint2 u; } o1;
            o1.b[0] = f2bf(v1.x); o1.b[1] = f2bf(v1.y); o1.b[2] = f2bf(v1.z); o1.b[3] = f2bf(v1.w);
            *(uint2*)(sB + (brr + 16 * i) * 64 + bcc) = o1.u;
        }
        __syncthreads();
#pragma unroll
        for (int ks = 0; ks < 2; ++ks) {
            const int kk = ks * 32 + lk;
            bf16x8 af[4], bfr[2];
#pragma unroll
            for (int i = 0; i < 4; ++i)
                af[i] = *(const bf16x8*)(sA + (wm + i * 16 + lr) * 64 + kk);
#pragma unroll
            for (int j = 0; j < 2; ++j)
                bfr[j] = *(const bf16x8*)(sB + (wn + j * 16 + lr) * 64 + kk);
#pragma unroll
            for (int i = 0; i < 4; ++i)
#pragma unroll
                for (int j = 0; j < 2; ++j)
                    acc[i][j] = __builtin_amdgcn_mfma_f32_16x16x32_bf16(af[i], bfr[j], acc[i][j], 0, 0, 0);
        }
    }

    const int q4 = (lane >> 4) * 4;
#pragma unroll
    for (int i = 0; i < 4; ++i) {
#pragma unroll
        for (int r = 0; r < 4; ++r) {
            const int row = wm + i * 16 + q4 + r;
            if (m0 + row < ne) {
                const int tok = btok[seg0 + m0 + row];
                float* op = out + (size_t)tok * kH + n0 + wn + (lane & 15);
#pragma unroll
                for (int j = 0; j < 2; ++j)
                    atomicAdd(op + j * 16, acc[i][j][r]);
            }
        }
    }
}

extern "C" void kernel_launch(void* const* d_in, const int* in_sizes, int n_in,
                              void* d_out, int out_size, void* d_ws, size_t ws_size,
                              hipStream_t stream) {
    const float* x  = (const float*)d_in[0];
    const float* gw = (const float*)d_in[1];
    const float* W1 = (const float*)d_in[2];
    const float* Up = (const float*)d_in[3];
    const float* W2 = (const float*)d_in[4];
    float* out = (float*)d_out;

    // workspace layout (~80 MB)
    char* ws = (char*)d_ws;
    size_t o = 0;
    __bf16* xb   = (__bf16*)(ws + o); o += (size_t)kT * kH * 2;          // 33.5 MB
    __bf16* hbuf = (__bf16*)(ws + o); o += (size_t)(2 * kT) * kI * 2;    // 46.1 MB
    int*   t_ids = (int*)(ws + o);    o += (size_t)(2 * kT) * 4;
    float* t_w   = (float*)(ws + o);  o += (size_t)(2 * kT) * 4;
    int*   btok  = (int*)(ws + o);    o += (size_t)(2 * kT) * 4;
    float* bw    = (float*)(ws + o);  o += (size_t)(2 * kT) * 4;
    int*   counts = (int*)(ws + o);   o += 64;
    int*   offs   = (int*)(ws + o);   o += 128;
    int*   fill   = (int*)(ws + o);   o += 64;

    hipMemsetAsync(out, 0, (size_t)kT * kH * sizeof(float), stream);
    hipMemsetAsync(counts, 0, kE * sizeof(int), stream);

    cvt_x_kernel<<<(kT * kH / 8) / 256, 256, 0, stream>>>(x, xb);
    gate_kernel<<<kT / 4, 256, 0, stream>>>(x, gw, t_ids, t_w, counts);
    scan_kernel<<<1, 64, 0, stream>>>(counts, offs, fill);
    scatter_kernel<<<(kT + 255) / 256, 256, 0, stream>>>(t_ids, t_w, fill, btok, bw);

    dim3 g1(kI / 64, 64, kE);   // y covers worst-case ne=8192 rows / BM=128
    gemm1_kernel<<<g1, 256, 0, stream>>>(xb, W1, Up, btok, bw, offs, hbuf);
    dim3 g2(kH / 64, 64, kE);
    gemm2_kernel<<<g2, 256, 0, stream>>>(hbuf, W2, btok, offs, out);
}